// Round 3
// baseline (110.962 us; speedup 1.0000x reference)
//
#include <hip/hip_runtime.h>

// MeanAggregator: out[b,:] = mean over UNIQUE cols c in row-segment b of embed[c,:]
// row_idx sorted ascending; duplicate (row,col) pairs count once (.set semantics).
//
// B = 4096 rows, U = 50000, D = 300, E = 131072 (avg deg 32, max ~60).
//
// v3b: SINGLE fused kernel (no build_rowptr dispatch, no workspace).
//  - per-wave 64-lane-parallel lower_bound over sorted row_idx finds the row
//    segment in 3 probe rounds (replaces the CSR build kernel entirely)
//  - speculative gather: raw col list staged to LDS immediately (no
//    ballot/rank compaction on the critical path); gather sums ALL deg
//    entries; duplicate contributions (expected ~0.01/row) are subtracted in
//    a rare wave-uniform correction pass; divisor = deg - ndup
//  - generic chunked-dedup fallback for deg >= 64 (essentially never taken)
//  - gather geometry unchanged from v1: full-wave float4 loads, lane t covers
//    chunk t, lanes 0..10 also chunk 64+t (75 chunks = 300 f32), 4-deep unroll

#define DFEAT  300
#define NCHUNK 75        // DFEAT / 4
#define CAP    128       // per-wave staged-col capacity
#define WPB    4         // waves per 256-thread block (1 row per wave)

// first index in arr[0..E) with arr[idx] >= t  (arr sorted ascending)
__device__ __forceinline__ int wave_lower_bound(
    const int* __restrict__ arr, int E, int t, int lane)
{
    int lo = 0, hi = E;                      // lower_bound in [lo, hi]
    while (hi - lo > 64) {
        const int span = hi - lo;
        const int p    = lo + (int)(((long long)span * (long long)lane) >> 6); // lane0 -> lo
        const int v    = arr[p];
        const unsigned long long m = __ballot(v < t);
        if (m == 0) return lo;               // arr[lo] >= t  ->  lb == lo
        const int k   = 63 - __clzll(m);     // last lane with v < t
        const int pk  = __shfl(p, k);
        const int pk1 = __shfl(p, (k + 1) & 63);
        lo = pk + 1;                         // lb > p_k
        if (k < 63) hi = pk1;                // arr[p_{k+1}] >= t -> lb <= p_{k+1}
    }
    const int p = lo + lane;
    const int v = (p < hi) ? arr[p] : 0x7fffffff;
    const unsigned long long m = __ballot(v < t);
    return lo + (int)__popcll(m);            // sorted -> prefix count
}

__global__ __launch_bounds__(256) void mean_agg_fused(
    const int* __restrict__ row_idx,
    const int* __restrict__ col_idx,
    const float* __restrict__ embed,
    float* __restrict__ out,
    int E, int B)
{
    const int lane = threadIdx.x & 63;
    const int w    = threadIdx.x >> 6;
    const int b    = blockIdx.x * WPB + w;
    if (b >= B) return;

    __shared__ int s_cols[WPB][CAP];

    const int start = wave_lower_bound(row_idx, E, b, lane);

    // combined row-membership probe + col load for the first chunk
    const int  i0    = start + lane;
    const bool inE   = (i0 < E);
    const int  rv    = inE ? row_idx[i0] : 0x7fffffff;
    const int  c0raw = inE ? col_idx[i0] : -1;
    const unsigned long long mrow = __ballot(rv == b);   // prefix mask
    const int deg0 = (int)__popcll(mrow);                // min(deg, 64)

    int n;                        // entries staged in s_cols to accumulate
    int cnt;                      // unique count (divisor)
    unsigned long long mdup = 0;  // fast-path duplicate-extra lanes

    if (deg0 < 64) {
        // ---- fast path: whole row fits one chunk; stage RAW cols now ----
        n = deg0;
        s_cols[w][lane] = c0raw;
        bool dup = false;
        for (int j = 0; j < deg0 - 1; ++j) {
            const int cj = __shfl(c0raw, j);
            dup = dup || ((j < lane) && (cj == c0raw));
        }
        dup  = dup && (lane < deg0);
        mdup = __ballot(dup);
        cnt  = deg0 - (int)__popcll(mdup);
    } else {
        // ---- generic fallback (deg >= 64): exact chunked dedup+compact ----
        const int end = wave_lower_bound(row_idx, E, b + 1, lane);
        const int deg = end - start;
        cnt = 0;
        for (int base = 0; base < deg; base += 64) {
            const int  i     = base + lane;
            const bool valid = (i < deg);
            const int  c     = valid ? col_idx[start + i] : -1;
            bool dup = false;
            for (int q = 0; q < cnt; ++q) dup = dup || (s_cols[w][q] == c);
            const int jmax = (deg - base - 1 < 63) ? (deg - base - 1) : 63;
            for (int j = 0; j < jmax; ++j) {
                const int cj = __shfl(c, j);
                dup = dup || ((j < lane) && (cj == c));
            }
            const unsigned long long m = __ballot(valid && !dup);
            const int rank = (int)__popcll(m & ((1ull << lane) - 1ull));
            if (valid && !dup) {
                const int p = cnt + rank;
                if (p < CAP) s_cols[w][p] = c;
            }
            cnt += (int)__popcll(m);
        }
        if (cnt > CAP) cnt = CAP;   // unreachable for this dataset; safety only
        n = cnt;
    }

    // ---- gather over s_cols[w][0..n): 4-deep unrolled, branch-free ----
    const bool hi = (lane < NCHUNK - 64);   // lanes 0..10 cover chunks 64..74
    float4 a0 = {0.f, 0.f, 0.f, 0.f};
    float4 a1 = {0.f, 0.f, 0.f, 0.f};

    int u = 0;
    for (; u + 4 <= n; u += 4) {
        const float4* __restrict__ p0 = (const float4*)(embed + (size_t)s_cols[w][u    ] * DFEAT);
        const float4* __restrict__ p1 = (const float4*)(embed + (size_t)s_cols[w][u + 1] * DFEAT);
        const float4* __restrict__ p2 = (const float4*)(embed + (size_t)s_cols[w][u + 2] * DFEAT);
        const float4* __restrict__ p3 = (const float4*)(embed + (size_t)s_cols[w][u + 3] * DFEAT);
        const float4 v0 = p0[lane];
        const float4 v1 = p1[lane];
        const float4 v2 = p2[lane];
        const float4 v3 = p3[lane];
        if (hi) {
            const float4 h0 = p0[lane + 64];
            const float4 h1 = p1[lane + 64];
            const float4 h2 = p2[lane + 64];
            const float4 h3 = p3[lane + 64];
            a1.x += h0.x + h1.x + h2.x + h3.x;
            a1.y += h0.y + h1.y + h2.y + h3.y;
            a1.z += h0.z + h1.z + h2.z + h3.z;
            a1.w += h0.w + h1.w + h2.w + h3.w;
        }
        a0.x += v0.x + v1.x + v2.x + v3.x;
        a0.y += v0.y + v1.y + v2.y + v3.y;
        a0.z += v0.z + v1.z + v2.z + v3.z;
        a0.w += v0.w + v1.w + v2.w + v3.w;
    }
    for (; u < n; ++u) {
        const float4* __restrict__ p0 = (const float4*)(embed + (size_t)s_cols[w][u] * DFEAT);
        const float4 v0 = p0[lane];
        a0.x += v0.x; a0.y += v0.y; a0.z += v0.z; a0.w += v0.w;
        if (hi) {
            const float4 h0 = p0[lane + 64];
            a1.x += h0.x; a1.y += h0.y; a1.z += h0.z; a1.w += h0.w;
        }
    }

    // ---- subtract duplicate extras (fast path; wave-uniform, rare) ----
    if (mdup) {
        unsigned long long m = mdup;
        while (m) {
            const int d = (int)__builtin_ctzll(m);
            m &= m - 1;
            const int cd = s_cols[w][d];
            const float4* __restrict__ p = (const float4*)(embed + (size_t)cd * DFEAT);
            const float4 v = p[lane];
            a0.x -= v.x; a0.y -= v.y; a0.z -= v.z; a0.w -= v.w;
            if (hi) {
                const float4 h = p[lane + 64];
                a1.x -= h.x; a1.y -= h.y; a1.z -= h.z; a1.w -= h.w;
            }
        }
    }

    // ---- scale + store ----
    const float s = (cnt > 0) ? (1.0f / (float)cnt) : 0.0f;
    float4* __restrict__ orow = (float4*)(out + (size_t)b * DFEAT);
    float4 r0; r0.x = a0.x * s; r0.y = a0.y * s; r0.z = a0.z * s; r0.w = a0.w * s;
    orow[lane] = r0;
    if (hi) {
        float4 r1; r1.x = a1.x * s; r1.y = a1.y * s; r1.z = a1.z * s; r1.w = a1.w * s;
        orow[lane + 64] = r1;
    }
}

extern "C" void kernel_launch(void* const* d_in, const int* in_sizes, int n_in,
                              void* d_out, int out_size, void* d_ws, size_t ws_size,
                              hipStream_t stream) {
    const int*   row_idx = (const int*)  d_in[0];
    const int*   col_idx = (const int*)  d_in[1];
    const float* embed   = (const float*)d_in[2];
    float*       out     = (float*)      d_out;

    const int E = in_sizes[0];            // 131072
    const int B = out_size / DFEAT;       // 4096

    mean_agg_fused<<<(B + WPB - 1) / WPB, 256, 0, stream>>>(
        row_idx, col_idx, embed, out, E, B);
}